// Round 4
// baseline (442.160 us; speedup 1.0000x reference)
//
#include <hip/hip_runtime.h>
#include <math.h>

// ---------------------------------------------------------------------------
// PolicyNet scoring, bf16-MFMA, zero-barrier wave-independent main (round 4).
//   rel = emb[action_ids]                          [A,128] gather
//   att = softmax_l(REL @ Q^T)                     [A,64]   (MFMA G1)
//   question = P @ Q                               [A,128]  (MFMA G2)
//   hidden = relu(h1 + question @ W1q^T)           [A,128]  (MFMA G3)
//   out = hidden @ W2^T + b2                       [A,128]  (MFMA G4)
//   scores = sum(rel*out,-1); softmax over A
//
// k_cvt pre-converts W1q/W2/Q/QT to bf16 in d_ws in B-fragment layouts
// ([col][k] row-major, k contiguous), so k_main loads all MFMA B-operands
// straight from global (L1/L2 broadcast across waves). Each wave owns 16
// actions end-to-end; P/QUEST/HID round-trip through wave-PRIVATE LDS
// (same-wave DS ordering, no __syncthreads anywhere in k_main).
//
// mfma_f32_16x16x32_bf16 maps (m89-verified):
//   A: row=lane&15, k=8*(lane>>4)+j    B: col=lane&15, same k
//   C/D: col=lane&15, row=4*(lane>>4)+reg
// ---------------------------------------------------------------------------

#define BA   64
#define NTHR 256
typedef unsigned short ushort_t;
typedef float  f32x4  __attribute__((ext_vector_type(4)));
typedef short  bf16x8 __attribute__((ext_vector_type(8)));

// per-wave LDS (ushort units): REL [16][136] then SCR [16][136] (P/QUEST/HID)
#define WSTRIDE 4352            // 2*2176 per wave
#define LDS_USH (4 * WSTRIDE)   // 34816 B total

__device__ __forceinline__ ushort_t f2bf(float f) {   // RNE
    unsigned int u = __float_as_uint(f);
    return (ushort_t)((u + 0x7fffu + ((u >> 16) & 1u)) >> 16);
}
__device__ __forceinline__ float bf2f(ushort_t h) {
    return __uint_as_float(((unsigned int)h) << 16);
}

// h1[j] = b1[j] + sum_{k<128} W1[j][k] * hist[k]
__global__ void k_prep(const float* __restrict__ hist, const float* __restrict__ W1,
                       const float* __restrict__ b1, float* __restrict__ h1)
{
    const int lane = threadIdx.x & 63;
    const int w    = threadIdx.x >> 6;
    const float h0  = hist[lane];
    const float h64 = hist[64 + lane];
    #pragma unroll 4
    for (int r = 0; r < 32; ++r) {
        const int j = w * 32 + r;
        float p = fmaf(W1[j * 256 + lane], h0, W1[j * 256 + 64 + lane] * h64);
        #pragma unroll
        for (int o = 1; o < 64; o <<= 1) p += __shfl_xor(p, o);
        if (lane == 0) h1[j] = b1[j] + p;
    }
}

// Convert W1q/W2/Q/QT to bf16 B-fragment layouts. 49152 elems, grid 192x256.
__global__ void k_cvt(const float* __restrict__ Qg, const float* __restrict__ W1,
                      const float* __restrict__ W2,
                      ushort_t* __restrict__ Qbf, ushort_t* __restrict__ QTbf,
                      ushort_t* __restrict__ W1bf, ushort_t* __restrict__ W2bf)
{
    const int i = blockIdx.x * 256 + threadIdx.x;
    if (i < 16384) {                         // W1bf[j][d] = W1[j][128+d]
        W1bf[i] = f2bf(W1[(i >> 7) * 256 + 128 + (i & 127)]);
    } else if (i < 32768) {                  // W2bf[d][j] = W2[d][j]
        const int k = i - 16384;
        W2bf[k] = f2bf(W2[k]);
    } else if (i < 40960) {                  // Qbf[l][d] = Q[l][d]
        const int k = i - 32768;
        Qbf[k] = f2bf(Qg[k]);
    } else {                                 // QTbf[d][l] = Q[l][d]
        const int k = i - 40960;
        const int d = k >> 6, l = k & 63;
        QTbf[k] = f2bf(Qg[l * 128 + d]);
    }
}

__global__ void __launch_bounds__(NTHR, 4)
k_main(const int* __restrict__ action_ids,
       const float* __restrict__ emb,
       const float* __restrict__ b2,
       const float* __restrict__ h1g,
       const ushort_t* __restrict__ Qbf,
       const ushort_t* __restrict__ QTbf,
       const ushort_t* __restrict__ W1bf,
       const ushort_t* __restrict__ W2bf,
       float* __restrict__ scores,
       float* __restrict__ mb,
       float* __restrict__ sb,
       int A)
{
    __shared__ __align__(16) ushort_t L[LDS_USH];
    const int tid  = threadIdx.x;
    const int w    = tid >> 6;
    const int lane = tid & 63;
    const int c    = lane & 15;         // frag col / A-row select
    const int g    = lane >> 4;         // frag k-block / D row-group
    ushort_t* RELw = &L[w * WSTRIDE];
    ushort_t* SCRw = &L[w * WSTRIDE + 2176];
    const int a0   = blockIdx.x * BA + 16 * w;   // wave's first action

    // ---- gather: REL row c (quarter g) -> A-frags + wave-private LDS ----
    bf16x8 relA[4];
    {
        const int ga  = a0 + c;
        const int rid = (ga < A) ? action_ids[ga] : 0;
        const float* er = emb + (size_t)rid * 128;
        #pragma unroll
        for (int ks = 0; ks < 4; ++ks) {
            const float4 v0 = *(const float4*)&er[ks * 32 + g * 8];
            const float4 v1 = *(const float4*)&er[ks * 32 + g * 8 + 4];
            union { bf16x8 v; ushort_t u[8]; } p;
            p.u[0] = f2bf(v0.x); p.u[1] = f2bf(v0.y);
            p.u[2] = f2bf(v0.z); p.u[3] = f2bf(v0.w);
            p.u[4] = f2bf(v1.x); p.u[5] = f2bf(v1.y);
            p.u[6] = f2bf(v1.z); p.u[7] = f2bf(v1.w);
            relA[ks] = p.v;
            *(bf16x8*)&RELw[c * 136 + ks * 32 + g * 8] = p.v;
        }
    }

    // ---- G1: ATT[16][64] = REL @ Q^T (K=128), B from global Qbf ----
    f32x4 att[4] = {};
    #pragma unroll
    for (int ks = 0; ks < 4; ++ks)
        #pragma unroll
        for (int nt = 0; nt < 4; ++nt) {
            const bf16x8 bfr = *(const bf16x8*)&Qbf[(16*nt + c) * 128 + ks*32 + g*8];
            att[nt] = __builtin_amdgcn_mfma_f32_16x16x32_bf16(relA[ks], bfr, att[nt], 0, 0, 0);
        }

    // ---- softmax over l; P -> SCRw as [a][72] bf16 ----
    {
        float m[4] = { -INFINITY, -INFINITY, -INFINITY, -INFINITY };
        #pragma unroll
        for (int nt = 0; nt < 4; ++nt)
            #pragma unroll
            for (int r = 0; r < 4; ++r) m[r] = fmaxf(m[r], att[nt][r]);
        #pragma unroll
        for (int r = 0; r < 4; ++r) {
            m[r] = fmaxf(m[r], __shfl_xor(m[r], 1));
            m[r] = fmaxf(m[r], __shfl_xor(m[r], 2));
            m[r] = fmaxf(m[r], __shfl_xor(m[r], 4));
            m[r] = fmaxf(m[r], __shfl_xor(m[r], 8));
        }
        float s[4] = { 0.f, 0.f, 0.f, 0.f };
        #pragma unroll
        for (int nt = 0; nt < 4; ++nt)
            #pragma unroll
            for (int r = 0; r < 4; ++r) {
                att[nt][r] = __expf(att[nt][r] - m[r]);
                s[r] += att[nt][r];
            }
        #pragma unroll
        for (int r = 0; r < 4; ++r) {
            s[r] += __shfl_xor(s[r], 1);
            s[r] += __shfl_xor(s[r], 2);
            s[r] += __shfl_xor(s[r], 4);
            s[r] += __shfl_xor(s[r], 8);
            s[r] = 1.f / s[r];
        }
        #pragma unroll
        for (int nt = 0; nt < 4; ++nt)
            #pragma unroll
            for (int r = 0; r < 4; ++r)
                SCRw[(4*g + r) * 72 + 16*nt + c] = f2bf(att[nt][r] * s[r]);
    }

    // ---- G2: QUEST[16][128] = P @ Q (K=64), A from SCRw, B from QTbf ----
    f32x4 qacc[8] = {};
    #pragma unroll
    for (int ks = 0; ks < 2; ++ks) {
        const bf16x8 afr = *(const bf16x8*)&SCRw[c * 72 + ks*32 + g*8];
        #pragma unroll
        for (int nt = 0; nt < 8; ++nt) {
            const bf16x8 bfr = *(const bf16x8*)&QTbf[(16*nt + c) * 64 + ks*32 + g*8];
            qacc[nt] = __builtin_amdgcn_mfma_f32_16x16x32_bf16(afr, bfr, qacc[nt], 0, 0, 0);
        }
    }
    // QUEST -> SCRw as [a][136] bf16 (P fully consumed above; same-wave order)
    #pragma unroll
    for (int nt = 0; nt < 8; ++nt)
        #pragma unroll
        for (int r = 0; r < 4; ++r)
            SCRw[(4*g + r) * 136 + 16*nt + c] = f2bf(qacc[nt][r]);

    // ---- G3: HID = relu(h1 + QUEST @ W1q^T), B from global W1bf ----
    f32x4 hacc[8] = {};
    #pragma unroll
    for (int ks = 0; ks < 4; ++ks) {
        const bf16x8 afr = *(const bf16x8*)&SCRw[c * 136 + ks*32 + g*8];
        #pragma unroll
        for (int nt = 0; nt < 8; ++nt) {
            const bf16x8 bfr = *(const bf16x8*)&W1bf[(16*nt + c) * 128 + ks*32 + g*8];
            hacc[nt] = __builtin_amdgcn_mfma_f32_16x16x32_bf16(afr, bfr, hacc[nt], 0, 0, 0);
        }
    }
    #pragma unroll
    for (int nt = 0; nt < 8; ++nt) {
        const float hb = h1g[16*nt + c];
        #pragma unroll
        for (int r = 0; r < 4; ++r)
            SCRw[(4*g + r) * 136 + 16*nt + c] = f2bf(fmaxf(hacc[nt][r] + hb, 0.f));
    }

    // ---- G4: OUT = HID @ W2^T + b2, B from global W2bf; score=sum(REL*OUT) --
    f32x4 oacc[8] = {};
    #pragma unroll
    for (int ks = 0; ks < 4; ++ks) {
        const bf16x8 afr = *(const bf16x8*)&SCRw[c * 136 + ks*32 + g*8];
        #pragma unroll
        for (int nt = 0; nt < 8; ++nt) {
            const bf16x8 bfr = *(const bf16x8*)&W2bf[(16*nt + c) * 128 + ks*32 + g*8];
            oacc[nt] = __builtin_amdgcn_mfma_f32_16x16x32_bf16(afr, bfr, oacc[nt], 0, 0, 0);
        }
    }
    float sacc[4] = { 0.f, 0.f, 0.f, 0.f };
    #pragma unroll
    for (int nt = 0; nt < 8; ++nt) {
        const float bb = b2[16*nt + c];
        #pragma unroll
        for (int r = 0; r < 4; ++r) {
            const float ov = oacc[nt][r] + bb;
            const float rv = bf2f(RELw[(4*g + r) * 136 + 16*nt + c]);
            sacc[r] = fmaf(ov, rv, sacc[r]);
        }
    }
    #pragma unroll
    for (int r = 0; r < 4; ++r) {        // reduce over d (c-lanes)
        sacc[r] += __shfl_xor(sacc[r], 1);
        sacc[r] += __shfl_xor(sacc[r], 2);
        sacc[r] += __shfl_xor(sacc[r], 4);
        sacc[r] += __shfl_xor(sacc[r], 8);
    }
    if (c == 0) {
        #pragma unroll
        for (int r = 0; r < 4; ++r) {
            const int ga = a0 + 4*g + r;
            if (ga < A) scores[ga] = sacc[r];
        }
    }

    // ---- per-wave softmax partials over this wave's 16 actions ----
    {
        float m = -INFINITY;
        #pragma unroll
        for (int r = 0; r < 4; ++r)
            if (a0 + 4*g + r < A) m = fmaxf(m, sacc[r]);
        m = fmaxf(m, __shfl_xor(m, 16));
        m = fmaxf(m, __shfl_xor(m, 32));
        float es = 0.f;
        #pragma unroll
        for (int r = 0; r < 4; ++r)
            if (a0 + 4*g + r < A) es += __expf(sacc[r] - m);
        es += __shfl_xor(es, 16);           // sum over g only (c-lanes hold
        es += __shfl_xor(es, 32);           // identical copies post-reduce)
        if (lane == 0) {
            const int idx = blockIdx.x * 4 + w;
            mb[idx] = m;
            sb[idx] = es;
        }
    }
}

// Combine per-wave (m, s) partials into global M and 1/S.
__global__ void k_combine(const float* __restrict__ mb, const float* __restrict__ sb,
                          int n, float* __restrict__ MS)
{
    __shared__ float red[256];
    const int tid = threadIdx.x;
    float m = -INFINITY;
    for (int i = tid; i < n; i += 256) m = fmaxf(m, mb[i]);
    red[tid] = m; __syncthreads();
    for (int s = 128; s > 0; s >>= 1) {
        if (tid < s) red[tid] = fmaxf(red[tid], red[tid + s]);
        __syncthreads();
    }
    const float M = red[0];
    __syncthreads();
    float sum = 0.f;
    for (int i = tid; i < n; i += 256) sum += sb[i] * __expf(mb[i] - M);
    red[tid] = sum; __syncthreads();
    for (int s = 128; s > 0; s >>= 1) {
        if (tid < s) red[tid] += red[tid + s];
        __syncthreads();
    }
    if (tid == 0) { MS[0] = M; MS[1] = 1.f / red[0]; }
}

// In-place: d_out holds raw scores; replace with softmax.
__global__ void k_norm(const float* __restrict__ scores, const float* __restrict__ MS,
                       float* __restrict__ out, int A)
{
    const int i = blockIdx.x * blockDim.x + threadIdx.x;
    if (i < A) out[i] = __expf(scores[i] - MS[0]) * MS[1];
}

extern "C" void kernel_launch(void* const* d_in, const int* in_sizes, int n_in,
                              void* d_out, int out_size, void* d_ws, size_t ws_size,
                              hipStream_t stream)
{
    const int*   action_ids = (const int*)  d_in[0];
    const float* emb        = (const float*)d_in[1];
    const float* Qg         = (const float*)d_in[2];
    const float* hist       = (const float*)d_in[3];
    const float* W1         = (const float*)d_in[4];
    const float* b1         = (const float*)d_in[5];
    const float* W2         = (const float*)d_in[6];
    const float* b2         = (const float*)d_in[7];
    float* out = (float*)d_out;
    const int A    = in_sizes[0];
    const int nblk = (A + BA - 1) / BA;
    const int npar = nblk * 4;                 // per-wave partials

    // Workspace (floats): h1[128] | MS[2] | pad | mb[npar] | sb[npar] | bf16 arena
    float* ws  = (float*)d_ws;
    float* h1  = ws;                           // 128
    float* MS  = ws + 128;                     // 2
    const int nal = (npar + 255) & ~255;       // 6400 for A=100000
    float* mbp = ws + 256;
    float* sbp = mbp + nal;
    ushort_t* u0   = (ushort_t*)(sbp + nal);   // 16B-aligned
    ushort_t* Qbf  = u0;                       // [64][128]  = 8192
    ushort_t* QTbf = u0 + 8192;                // [128][64]  = 8192
    ushort_t* W1bf = u0 + 16384;               // [128][128] = 16384
    ushort_t* W2bf = u0 + 32768;               // [128][128] = 16384
    (void)n_in; (void)out_size; (void)ws_size;

    k_prep<<<1, 256, 0, stream>>>(hist, W1, b1, h1);
    k_cvt <<<192, 256, 0, stream>>>(Qg, W1, W2, Qbf, QTbf, W1bf, W2bf);
    // raw scores land directly in d_out; normalized in-place afterwards
    k_main<<<nblk, NTHR, 0, stream>>>(action_ids, emb, b2, h1,
                                      Qbf, QTbf, W1bf, W2bf,
                                      out, mbp, sbp, A);
    k_combine<<<1, 256, 0, stream>>>(mbp, sbp, npar, MS);
    k_norm<<<(A + 255) / 256, 256, 0, stream>>>(out, MS, out, A);
}

// Round 5
// 440.601 us; speedup vs baseline: 1.0035x; 1.0035x over previous
//
#include <hip/hip_runtime.h>
#include <math.h>

// ---------------------------------------------------------------------------
// PolicyNet scoring, bf16-MFMA, zero-barrier wave-independent main (round 5).
// Identical algorithm/layouts to round 4; changes:
//   * __launch_bounds__(256, 2): relax VGPR cap 128 -> 256 (round-4's
//     (256,4) forced spills-to-scratch inside the serial per-wave chain —
//     suspected cause of the 91->144us k_main regression).
//   * k_prep merged into k_cvt (block 192) — one fewer serialized launch.
//
//   rel = emb[action_ids]                          [A,128] gather
//   att = softmax_l(REL @ Q^T)                     [A,64]   (MFMA G1)
//   question = P @ Q                               [A,128]  (MFMA G2)
//   hidden = relu(h1 + question @ W1q^T)           [A,128]  (MFMA G3)
//   out = hidden @ W2^T + b2                       [A,128]  (MFMA G4)
//   scores = sum(rel*out,-1); softmax over A
//
// k_cvt pre-converts W1q/W2/Q/QT to bf16 in d_ws in B-fragment layouts
// ([col][k] row-major, k contiguous); k_main loads all MFMA B-operands
// straight from global (L1/L2 broadcast). Each wave owns 16 actions
// end-to-end; P/QUEST/HID round-trip through wave-PRIVATE LDS. No
// __syncthreads in k_main.
//
// mfma_f32_16x16x32_bf16 maps (m89-verified):
//   A: row=lane&15, k=8*(lane>>4)+j    B: col=lane&15, same k
//   C/D: col=lane&15, row=4*(lane>>4)+reg
// ---------------------------------------------------------------------------

#define BA   64
#define NTHR 256
typedef unsigned short ushort_t;
typedef float  f32x4  __attribute__((ext_vector_type(4)));
typedef short  bf16x8 __attribute__((ext_vector_type(8)));

// per-wave LDS (ushort units): REL [16][136] then SCR [16][136] (P/QUEST/HID)
#define WSTRIDE 4352            // 2*2176 per wave
#define LDS_USH (4 * WSTRIDE)   // 34816 B total

__device__ __forceinline__ ushort_t f2bf(float f) {   // RNE
    unsigned int u = __float_as_uint(f);
    return (ushort_t)((u + 0x7fffu + ((u >> 16) & 1u)) >> 16);
}
__device__ __forceinline__ float bf2f(ushort_t h) {
    return __uint_as_float(((unsigned int)h) << 16);
}

// blocks 0..191: convert W1q/W2/Q/QT to bf16 B-fragment layouts (49152 elems).
// block 192:     h1[j] = b1[j] + sum_{k<128} W1[j][k] * hist[k]
__global__ void k_cvt(const float* __restrict__ Qg, const float* __restrict__ W1,
                      const float* __restrict__ W2,
                      const float* __restrict__ hist, const float* __restrict__ b1,
                      ushort_t* __restrict__ Qbf, ushort_t* __restrict__ QTbf,
                      ushort_t* __restrict__ W1bf, ushort_t* __restrict__ W2bf,
                      float* __restrict__ h1)
{
    if (blockIdx.x == 192) {                 // h1 prep (was k_prep)
        const int lane = threadIdx.x & 63;
        const int w    = threadIdx.x >> 6;
        const float h0  = hist[lane];
        const float h64 = hist[64 + lane];
        #pragma unroll 4
        for (int r = 0; r < 32; ++r) {
            const int j = w * 32 + r;
            float p = fmaf(W1[j * 256 + lane], h0, W1[j * 256 + 64 + lane] * h64);
            #pragma unroll
            for (int o = 1; o < 64; o <<= 1) p += __shfl_xor(p, o);
            if (lane == 0) h1[j] = b1[j] + p;
        }
        return;
    }
    const int i = blockIdx.x * 256 + threadIdx.x;
    if (i < 16384) {                         // W1bf[j][d] = W1[j][128+d]
        W1bf[i] = f2bf(W1[(i >> 7) * 256 + 128 + (i & 127)]);
    } else if (i < 32768) {                  // W2bf[d][j] = W2[d][j]
        const int k = i - 16384;
        W2bf[k] = f2bf(W2[k]);
    } else if (i < 40960) {                  // Qbf[l][d] = Q[l][d]
        const int k = i - 32768;
        Qbf[k] = f2bf(Qg[k]);
    } else {                                 // QTbf[d][l] = Q[l][d]
        const int k = i - 40960;
        const int d = k >> 6, l = k & 63;
        QTbf[k] = f2bf(Qg[l * 128 + d]);
    }
}

__global__ void __launch_bounds__(NTHR, 2)
k_main(const int* __restrict__ action_ids,
       const float* __restrict__ emb,
       const float* __restrict__ b2,
       const float* __restrict__ h1g,
       const ushort_t* __restrict__ Qbf,
       const ushort_t* __restrict__ QTbf,
       const ushort_t* __restrict__ W1bf,
       const ushort_t* __restrict__ W2bf,
       float* __restrict__ scores,
       float* __restrict__ mb,
       float* __restrict__ sb,
       int A)
{
    __shared__ __align__(16) ushort_t L[LDS_USH];
    const int tid  = threadIdx.x;
    const int w    = tid >> 6;
    const int lane = tid & 63;
    const int c    = lane & 15;         // frag col / A-row select
    const int g    = lane >> 4;         // frag k-block / D row-group
    ushort_t* RELw = &L[w * WSTRIDE];
    ushort_t* SCRw = &L[w * WSTRIDE + 2176];
    const int a0   = blockIdx.x * BA + 16 * w;   // wave's first action

    // ---- gather: REL row c (quarter g) -> A-frags + wave-private LDS ----
    bf16x8 relA[4];
    {
        const int ga  = a0 + c;
        const int rid = (ga < A) ? action_ids[ga] : 0;
        const float* er = emb + (size_t)rid * 128;
        #pragma unroll
        for (int ks = 0; ks < 4; ++ks) {
            const float4 v0 = *(const float4*)&er[ks * 32 + g * 8];
            const float4 v1 = *(const float4*)&er[ks * 32 + g * 8 + 4];
            union { bf16x8 v; ushort_t u[8]; } p;
            p.u[0] = f2bf(v0.x); p.u[1] = f2bf(v0.y);
            p.u[2] = f2bf(v0.z); p.u[3] = f2bf(v0.w);
            p.u[4] = f2bf(v1.x); p.u[5] = f2bf(v1.y);
            p.u[6] = f2bf(v1.z); p.u[7] = f2bf(v1.w);
            relA[ks] = p.v;
            *(bf16x8*)&RELw[c * 136 + ks * 32 + g * 8] = p.v;
        }
    }

    // ---- G1: ATT[16][64] = REL @ Q^T (K=128), B from global Qbf ----
    f32x4 att[4] = {};
    #pragma unroll
    for (int ks = 0; ks < 4; ++ks)
        #pragma unroll
        for (int nt = 0; nt < 4; ++nt) {
            const bf16x8 bfr = *(const bf16x8*)&Qbf[(16*nt + c) * 128 + ks*32 + g*8];
            att[nt] = __builtin_amdgcn_mfma_f32_16x16x32_bf16(relA[ks], bfr, att[nt], 0, 0, 0);
        }

    // ---- softmax over l; P -> SCRw as [a][72] bf16 ----
    {
        float m[4] = { -INFINITY, -INFINITY, -INFINITY, -INFINITY };
        #pragma unroll
        for (int nt = 0; nt < 4; ++nt)
            #pragma unroll
            for (int r = 0; r < 4; ++r) m[r] = fmaxf(m[r], att[nt][r]);
        #pragma unroll
        for (int r = 0; r < 4; ++r) {
            m[r] = fmaxf(m[r], __shfl_xor(m[r], 1));
            m[r] = fmaxf(m[r], __shfl_xor(m[r], 2));
            m[r] = fmaxf(m[r], __shfl_xor(m[r], 4));
            m[r] = fmaxf(m[r], __shfl_xor(m[r], 8));
        }
        float s[4] = { 0.f, 0.f, 0.f, 0.f };
        #pragma unroll
        for (int nt = 0; nt < 4; ++nt)
            #pragma unroll
            for (int r = 0; r < 4; ++r) {
                att[nt][r] = __expf(att[nt][r] - m[r]);
                s[r] += att[nt][r];
            }
        #pragma unroll
        for (int r = 0; r < 4; ++r) {
            s[r] += __shfl_xor(s[r], 1);
            s[r] += __shfl_xor(s[r], 2);
            s[r] += __shfl_xor(s[r], 4);
            s[r] += __shfl_xor(s[r], 8);
            s[r] = 1.f / s[r];
        }
        #pragma unroll
        for (int nt = 0; nt < 4; ++nt)
            #pragma unroll
            for (int r = 0; r < 4; ++r)
                SCRw[(4*g + r) * 72 + 16*nt + c] = f2bf(att[nt][r] * s[r]);
    }

    // ---- G2: QUEST[16][128] = P @ Q (K=64), A from SCRw, B from QTbf ----
    f32x4 qacc[8] = {};
    #pragma unroll
    for (int ks = 0; ks < 2; ++ks) {
        const bf16x8 afr = *(const bf16x8*)&SCRw[c * 72 + ks*32 + g*8];
        #pragma unroll
        for (int nt = 0; nt < 8; ++nt) {
            const bf16x8 bfr = *(const bf16x8*)&QTbf[(16*nt + c) * 64 + ks*32 + g*8];
            qacc[nt] = __builtin_amdgcn_mfma_f32_16x16x32_bf16(afr, bfr, qacc[nt], 0, 0, 0);
        }
    }
    // QUEST -> SCRw as [a][136] bf16 (P fully consumed above; same-wave order)
    #pragma unroll
    for (int nt = 0; nt < 8; ++nt)
        #pragma unroll
        for (int r = 0; r < 4; ++r)
            SCRw[(4*g + r) * 136 + 16*nt + c] = f2bf(qacc[nt][r]);

    // ---- G3: HID = relu(h1 + QUEST @ W1q^T), B from global W1bf ----
    f32x4 hacc[8] = {};
    #pragma unroll
    for (int ks = 0; ks < 4; ++ks) {
        const bf16x8 afr = *(const bf16x8*)&SCRw[c * 136 + ks*32 + g*8];
        #pragma unroll
        for (int nt = 0; nt < 8; ++nt) {
            const bf16x8 bfr = *(const bf16x8*)&W1bf[(16*nt + c) * 128 + ks*32 + g*8];
            hacc[nt] = __builtin_amdgcn_mfma_f32_16x16x32_bf16(afr, bfr, hacc[nt], 0, 0, 0);
        }
    }
    #pragma unroll
    for (int nt = 0; nt < 8; ++nt) {
        const float hb = h1g[16*nt + c];
        #pragma unroll
        for (int r = 0; r < 4; ++r)
            SCRw[(4*g + r) * 136 + 16*nt + c] = f2bf(fmaxf(hacc[nt][r] + hb, 0.f));
    }

    // ---- G4: OUT = HID @ W2^T + b2, B from global W2bf; score=sum(REL*OUT) --
    f32x4 oacc[8] = {};
    #pragma unroll
    for (int ks = 0; ks < 4; ++ks) {
        const bf16x8 afr = *(const bf16x8*)&SCRw[c * 136 + ks*32 + g*8];
        #pragma unroll
        for (int nt = 0; nt < 8; ++nt) {
            const bf16x8 bfr = *(const bf16x8*)&W2bf[(16*nt + c) * 128 + ks*32 + g*8];
            oacc[nt] = __builtin_amdgcn_mfma_f32_16x16x32_bf16(afr, bfr, oacc[nt], 0, 0, 0);
        }
    }
    float sacc[4] = { 0.f, 0.f, 0.f, 0.f };
    #pragma unroll
    for (int nt = 0; nt < 8; ++nt) {
        const float bb = b2[16*nt + c];
        #pragma unroll
        for (int r = 0; r < 4; ++r) {
            const float ov = oacc[nt][r] + bb;
            const float rv = bf2f(RELw[(4*g + r) * 136 + 16*nt + c]);
            sacc[r] = fmaf(ov, rv, sacc[r]);
        }
    }
    #pragma unroll
    for (int r = 0; r < 4; ++r) {        // reduce over d (c-lanes)
        sacc[r] += __shfl_xor(sacc[r], 1);
        sacc[r] += __shfl_xor(sacc[r], 2);
        sacc[r] += __shfl_xor(sacc[r], 4);
        sacc[r] += __shfl_xor(sacc[r], 8);
    }
    if (c == 0) {
        #pragma unroll
        for (int r = 0; r < 4; ++r) {
            const int ga = a0 + 4*g + r;
            if (ga < A) scores[ga] = sacc[r];
        }
    }

    // ---- per-wave softmax partials over this wave's 16 actions ----
    {
        float m = -INFINITY;
        #pragma unroll
        for (int r = 0; r < 4; ++r)
            if (a0 + 4*g + r < A) m = fmaxf(m, sacc[r]);
        m = fmaxf(m, __shfl_xor(m, 16));
        m = fmaxf(m, __shfl_xor(m, 32));
        float es = 0.f;
        #pragma unroll
        for (int r = 0; r < 4; ++r)
            if (a0 + 4*g + r < A) es += __expf(sacc[r] - m);
        es += __shfl_xor(es, 16);           // sum over g only (c-lanes hold
        es += __shfl_xor(es, 32);           // identical copies post-reduce)
        if (lane == 0) {
            const int idx = blockIdx.x * 4 + w;
            mb[idx] = m;
            sb[idx] = es;
        }
    }
}

// Combine per-wave (m, s) partials into global M and 1/S.
__global__ void k_combine(const float* __restrict__ mb, const float* __restrict__ sb,
                          int n, float* __restrict__ MS)
{
    __shared__ float red[256];
    const int tid = threadIdx.x;
    float m = -INFINITY;
    for (int i = tid; i < n; i += 256) m = fmaxf(m, mb[i]);
    red[tid] = m; __syncthreads();
    for (int s = 128; s > 0; s >>= 1) {
        if (tid < s) red[tid] = fmaxf(red[tid], red[tid + s]);
        __syncthreads();
    }
    const float M = red[0];
    __syncthreads();
    float sum = 0.f;
    for (int i = tid; i < n; i += 256) sum += sb[i] * __expf(mb[i] - M);
    red[tid] = sum; __syncthreads();
    for (int s = 128; s > 0; s >>= 1) {
        if (tid < s) red[tid] += red[tid + s];
        __syncthreads();
    }
    if (tid == 0) { MS[0] = M; MS[1] = 1.f / red[0]; }
}

// In-place: d_out holds raw scores; replace with softmax.
__global__ void k_norm(const float* __restrict__ scores, const float* __restrict__ MS,
                       float* __restrict__ out, int A)
{
    const int i = blockIdx.x * blockDim.x + threadIdx.x;
    if (i < A) out[i] = __expf(scores[i] - MS[0]) * MS[1];
}

extern "C" void kernel_launch(void* const* d_in, const int* in_sizes, int n_in,
                              void* d_out, int out_size, void* d_ws, size_t ws_size,
                              hipStream_t stream)
{
    const int*   action_ids = (const int*)  d_in[0];
    const float* emb        = (const float*)d_in[1];
    const float* Qg         = (const float*)d_in[2];
    const float* hist       = (const float*)d_in[3];
    const float* W1         = (const float*)d_in[4];
    const float* b1         = (const float*)d_in[5];
    const float* W2         = (const float*)d_in[6];
    const float* b2         = (const float*)d_in[7];
    float* out = (float*)d_out;
    const int A    = in_sizes[0];
    const int nblk = (A + BA - 1) / BA;
    const int npar = nblk * 4;                 // per-wave partials

    // Workspace (floats): h1[128] | MS[2] | pad | mb[npar] | sb[npar] | bf16 arena
    float* ws  = (float*)d_ws;
    float* h1  = ws;                           // 128
    float* MS  = ws + 128;                     // 2
    const int nal = (npar + 255) & ~255;       // 6400 for A=100000
    float* mbp = ws + 256;
    float* sbp = mbp + nal;
    ushort_t* u0   = (ushort_t*)(sbp + nal);   // 16B-aligned
    ushort_t* Qbf  = u0;                       // [64][128]  = 8192
    ushort_t* QTbf = u0 + 8192;                // [128][64]  = 8192
    ushort_t* W1bf = u0 + 16384;               // [128][128] = 16384
    ushort_t* W2bf = u0 + 32768;               // [128][128] = 16384
    (void)n_in; (void)out_size; (void)ws_size;

    k_cvt<<<193, 256, 0, stream>>>(Qg, W1, W2, hist, b1,
                                   Qbf, QTbf, W1bf, W2bf, h1);
    // raw scores land directly in d_out; normalized in-place afterwards
    k_main<<<nblk, NTHR, 0, stream>>>(action_ids, emb, b2, h1,
                                      Qbf, QTbf, W1bf, W2bf,
                                      out, mbp, sbp, A);
    k_combine<<<1, 256, 0, stream>>>(mbp, sbp, npar, MS);
    k_norm<<<(A + 255) / 256, 256, 0, stream>>>(out, MS, out, A);
}

// Round 7
// 373.162 us; speedup vs baseline: 1.1849x; 1.1807x over previous
//
#include <hip/hip_runtime.h>
#include <math.h>

// ---------------------------------------------------------------------------
// PolicyNet scoring, bf16-MFMA (round 7 = round 6 resubmit; round 6 never ran,
// GPUAcquisitionTimeout).
// Round 4/5 post-mortem: global per-MFMA B-fragment reads thrash L1 (98 KB
// working set vs 32 KB) -> L2-latency/MSHR bound, insensitive to VGPRs.
// Fix: stage B-operands in a single time-multiplexed LDS region (BT) via
// pure bf16 copies from the k_cvt-preconverted tables (no conversion VALU,
// unlike round 3), with stage-loads issued during the previous compute phase
// (T14 async-stage split). LDS 53.2 KB -> 3 blocks/CU (12 waves/CU).
//
//   rel = emb[action_ids]                          [A,128] gather
//   att = softmax_l(REL @ Q^T)                     [A,64]   (MFMA G1)
//   question = P @ Q                               [A,128]  (MFMA G2)
//   hidden = relu(h1 + question @ W1q^T)           [A,128]  (MFMA G3, 2 halves)
//   out = hidden @ W2^T + b2                       [A,128]  (MFMA G4, 2 halves)
//   scores = sum(rel*out,-1); softmax over A
//
// mfma_f32_16x16x32_bf16 maps (m89-verified, proven rounds 3-5):
//   A: row=lane&15, k=8*(lane>>4)+j    B: col=lane&15, same k
//   C/D: col=lane&15, row=4*(lane>>4)+reg
// All LDS strides are multiples of 8 ushorts (16 B) for ds_*_b128 alignment.
// ---------------------------------------------------------------------------

#define BA   64
#define NTHR 256
typedef unsigned short ushort_t;
typedef float  f32x4  __attribute__((ext_vector_type(4)));
typedef short  bf16x8 __attribute__((ext_vector_type(8)));

// LDS layout (ushort units):
//   BT  : staged B-table chunk, holds one of {Q[64][136], QT[128][72],
//         Wx half [64][136]} -> 9216 ush
//   REL : 4 waves x [16][136] = 8704 ush   (wave-private, live whole kernel)
//   SCR : 4 waves x [16][136] = 8704 ush   (wave-private P/QUEST/HID)
#define BT    0
#define RELo  9216
#define SCRo  17920
#define LDS_USH 26624            // 53248 B -> 3 blocks/CU

__device__ __forceinline__ ushort_t f2bf(float f) {   // RNE
    unsigned int u = __float_as_uint(f);
    return (ushort_t)((u + 0x7fffu + ((u >> 16) & 1u)) >> 16);
}
__device__ __forceinline__ float bf2f(ushort_t h) {
    return __uint_as_float(((unsigned int)h) << 16);
}

// staging: 1024 16-B chunks per fill, 4 per thread, held in stg[] registers
#define ST_LOAD128(SRC, OFF) do { _Pragma("unroll")                           \
    for (int it = 0; it < 4; ++it) { const int q = tid + 256 * it;            \
        stg[it] = *(const bf16x8*)&(SRC)[(OFF) + (q >> 4) * 128 + (q & 15) * 8]; } } while (0)
#define ST_WRITE136() do { _Pragma("unroll")                                  \
    for (int it = 0; it < 4; ++it) { const int q = tid + 256 * it;            \
        *(bf16x8*)&L[BT + (q >> 4) * 136 + (q & 15) * 8] = stg[it]; } } while (0)
#define ST_LOAD64(SRC) do { _Pragma("unroll")                                 \
    for (int it = 0; it < 4; ++it) { const int q = tid + 256 * it;            \
        stg[it] = *(const bf16x8*)&(SRC)[(q >> 3) * 64 + (q & 7) * 8]; } } while (0)
#define ST_WRITE72() do { _Pragma("unroll")                                   \
    for (int it = 0; it < 4; ++it) { const int q = tid + 256 * it;            \
        *(bf16x8*)&L[BT + (q >> 3) * 72 + (q & 7) * 8] = stg[it]; } } while (0)

// blocks 0..191: convert W1q/W2/Q/QT to bf16 B-fragment layouts (49152 elems).
// block 192:     h1[j] = b1[j] + sum_{k<128} W1[j][k] * hist[k]
__global__ void k_cvt(const float* __restrict__ Qg, const float* __restrict__ W1,
                      const float* __restrict__ W2,
                      const float* __restrict__ hist, const float* __restrict__ b1,
                      ushort_t* __restrict__ Qbf, ushort_t* __restrict__ QTbf,
                      ushort_t* __restrict__ W1bf, ushort_t* __restrict__ W2bf,
                      float* __restrict__ h1)
{
    if (blockIdx.x == 192) {                 // h1 prep
        const int lane = threadIdx.x & 63;
        const int w    = threadIdx.x >> 6;
        const float h0  = hist[lane];
        const float h64 = hist[64 + lane];
        #pragma unroll 4
        for (int r = 0; r < 32; ++r) {
            const int j = w * 32 + r;
            float p = fmaf(W1[j * 256 + lane], h0, W1[j * 256 + 64 + lane] * h64);
            #pragma unroll
            for (int o = 1; o < 64; o <<= 1) p += __shfl_xor(p, o);
            if (lane == 0) h1[j] = b1[j] + p;
        }
        return;
    }
    const int i = blockIdx.x * 256 + threadIdx.x;
    if (i < 16384) {                         // W1bf[j][d] = W1[j][128+d]
        W1bf[i] = f2bf(W1[(i >> 7) * 256 + 128 + (i & 127)]);
    } else if (i < 32768) {                  // W2bf[d][j] = W2[d][j]
        const int k = i - 16384;
        W2bf[k] = f2bf(W2[k]);
    } else if (i < 40960) {                  // Qbf[l][d] = Q[l][d]
        const int k = i - 32768;
        Qbf[k] = f2bf(Qg[k]);
    } else {                                 // QTbf[d][l] = Q[l][d]
        const int k = i - 40960;
        const int d = k >> 6, l = k & 63;
        QTbf[k] = f2bf(Qg[l * 128 + d]);
    }
}

__global__ void __launch_bounds__(NTHR, 3)
k_main(const int* __restrict__ action_ids,
       const float* __restrict__ emb,
       const float* __restrict__ b2,
       const float* __restrict__ h1g,
       const ushort_t* __restrict__ Qbf,
       const ushort_t* __restrict__ QTbf,
       const ushort_t* __restrict__ W1bf,
       const ushort_t* __restrict__ W2bf,
       float* __restrict__ scores,
       float* __restrict__ mb,
       float* __restrict__ sb,
       int A)
{
    __shared__ __align__(16) ushort_t L[LDS_USH];
    const int tid  = threadIdx.x;
    const int w    = tid >> 6;
    const int lane = tid & 63;
    const int c    = lane & 15;         // frag col / A-row select
    const int g    = lane >> 4;         // frag k-block / D row-group
    ushort_t* RELw = &L[RELo + w * 2176];
    ushort_t* SCRw = &L[SCRo + w * 2176];
    const int a0   = blockIdx.x * BA + 16 * w;   // wave's first action
    bf16x8 stg[4];

    // ---- P0: stage Q into BT; gather REL -> A-frags + wave-private LDS ----
    bf16x8 relA[4];
    {
        const int ga  = a0 + c;
        const int rid = (ga < A) ? action_ids[ga] : 0;
        const float* er = emb + (size_t)rid * 128;
        ST_LOAD128(Qbf, 0);
        #pragma unroll
        for (int ks = 0; ks < 4; ++ks) {
            const float4 v0 = *(const float4*)&er[ks * 32 + g * 8];
            const float4 v1 = *(const float4*)&er[ks * 32 + g * 8 + 4];
            union { bf16x8 v; ushort_t u[8]; } p;
            p.u[0] = f2bf(v0.x); p.u[1] = f2bf(v0.y);
            p.u[2] = f2bf(v0.z); p.u[3] = f2bf(v0.w);
            p.u[4] = f2bf(v1.x); p.u[5] = f2bf(v1.y);
            p.u[6] = f2bf(v1.z); p.u[7] = f2bf(v1.w);
            relA[ks] = p.v;
            *(bf16x8*)&RELw[c * 136 + ks * 32 + g * 8] = p.v;
        }
        ST_WRITE136();
    }
    __syncthreads();                                            // bar 1

    // ---- G1: ATT[16][64] = REL @ Q^T (K=128), B from BT (Q) ----
    f32x4 att[4] = {};
    ST_LOAD64(QTbf);                       // prefetch QT under G1
    #pragma unroll
    for (int ks = 0; ks < 4; ++ks)
        #pragma unroll
        for (int nt = 0; nt < 4; ++nt) {
            const bf16x8 bfr = *(const bf16x8*)&L[BT + (16*nt + c)*136 + ks*32 + g*8];
            att[nt] = __builtin_amdgcn_mfma_f32_16x16x32_bf16(relA[ks], bfr, att[nt], 0, 0, 0);
        }

    // ---- softmax over l; P -> SCRw as [16][72] bf16 ----
    {
        float m[4] = { -INFINITY, -INFINITY, -INFINITY, -INFINITY };
        #pragma unroll
        for (int nt = 0; nt < 4; ++nt)
            #pragma unroll
            for (int r = 0; r < 4; ++r) m[r] = fmaxf(m[r], att[nt][r]);
        #pragma unroll
        for (int r = 0; r < 4; ++r) {
            m[r] = fmaxf(m[r], __shfl_xor(m[r], 1));
            m[r] = fmaxf(m[r], __shfl_xor(m[r], 2));
            m[r] = fmaxf(m[r], __shfl_xor(m[r], 4));
            m[r] = fmaxf(m[r], __shfl_xor(m[r], 8));
        }
        float s[4] = { 0.f, 0.f, 0.f, 0.f };
        #pragma unroll
        for (int nt = 0; nt < 4; ++nt)
            #pragma unroll
            for (int r = 0; r < 4; ++r) {
                att[nt][r] = __expf(att[nt][r] - m[r]);
                s[r] += att[nt][r];
            }
        #pragma unroll
        for (int r = 0; r < 4; ++r) {
            s[r] += __shfl_xor(s[r], 1);
            s[r] += __shfl_xor(s[r], 2);
            s[r] += __shfl_xor(s[r], 4);
            s[r] += __shfl_xor(s[r], 8);
            s[r] = 1.f / s[r];
        }
        #pragma unroll
        for (int nt = 0; nt < 4; ++nt)
            #pragma unroll
            for (int r = 0; r < 4; ++r)
                SCRw[(4*g + r) * 72 + 16*nt + c] = f2bf(att[nt][r] * s[r]);
    }
    __syncthreads();                                            // bar 2 (Q dead)
    ST_WRITE72();                          // QT -> BT
    __syncthreads();                                            // bar 3

    // ---- G2: QUEST[16][128] = P @ Q (K=64), A from SCRw, B from BT (QT) ----
    f32x4 qacc[8] = {};
    ST_LOAD128(W1bf, 0);                   // prefetch W1a under G2
    #pragma unroll
    for (int ks = 0; ks < 2; ++ks) {
        const bf16x8 afr = *(const bf16x8*)&SCRw[c * 72 + ks*32 + g*8];
        #pragma unroll
        for (int nt = 0; nt < 8; ++nt) {
            const bf16x8 bfr = *(const bf16x8*)&L[BT + (16*nt + c)*72 + ks*32 + g*8];
            qacc[nt] = __builtin_amdgcn_mfma_f32_16x16x32_bf16(afr, bfr, qacc[nt], 0, 0, 0);
        }
    }
    // QUEST -> SCRw as [16][136] bf16 (P fully consumed; same-wave order)
    #pragma unroll
    for (int nt = 0; nt < 8; ++nt)
        #pragma unroll
        for (int r = 0; r < 4; ++r)
            SCRw[(4*g + r) * 136 + 16*nt + c] = f2bf(qacc[nt][r]);
    __syncthreads();                                            // bar 4 (QT dead)
    ST_WRITE136();                         // W1a -> BT
    __syncthreads();                                            // bar 5

    // ---- G3: HID = relu(h1 + QUEST @ W1q^T), two 64-row halves ----
    f32x4 hacc[8] = {};
    ST_LOAD128(W1bf, 8192);                // prefetch W1b under G3h1
    #pragma unroll
    for (int ks = 0; ks < 4; ++ks) {
        const bf16x8 afr = *(const bf16x8*)&SCRw[c * 136 + ks*32 + g*8];
        #pragma unroll
        for (int nt = 0; nt < 4; ++nt) {
            const bf16x8 bfr = *(const bf16x8*)&L[BT + (16*nt + c)*136 + ks*32 + g*8];
            hacc[nt] = __builtin_amdgcn_mfma_f32_16x16x32_bf16(afr, bfr, hacc[nt], 0, 0, 0);
        }
    }
    __syncthreads();                                            // bar 6
    ST_WRITE136();                         // W1b -> BT
    __syncthreads();                                            // bar 7
    ST_LOAD128(W2bf, 0);                   // prefetch W2a under G3h2
    #pragma unroll
    for (int ks = 0; ks < 4; ++ks) {
        const bf16x8 afr = *(const bf16x8*)&SCRw[c * 136 + ks*32 + g*8];
        #pragma unroll
        for (int nt = 0; nt < 4; ++nt) {
            const bf16x8 bfr = *(const bf16x8*)&L[BT + (16*nt + c)*136 + ks*32 + g*8];
            hacc[4 + nt] = __builtin_amdgcn_mfma_f32_16x16x32_bf16(afr, bfr, hacc[4 + nt], 0, 0, 0);
        }
    }
    // h1 + relu; HID -> SCRw [16][136] (all own-wave QUEST reads done above)
    #pragma unroll
    for (int i = 0; i < 8; ++i) {
        const int j = (i >> 2) * 64 + (i & 3) * 16 + c;
        const float hb = h1g[j];
        #pragma unroll
        for (int r = 0; r < 4; ++r)
            SCRw[(4*g + r) * 136 + j] = f2bf(fmaxf(hacc[i][r] + hb, 0.f));
    }
    __syncthreads();                                            // bar 8 (W1b dead)
    ST_WRITE136();                         // W2a -> BT
    __syncthreads();                                            // bar 9

    // ---- G4: OUT = HID @ W2^T + b2, two halves; score = sum(REL*OUT) ----
    float sacc[4] = { 0.f, 0.f, 0.f, 0.f };
    {
        f32x4 oacc[4] = {};
        ST_LOAD128(W2bf, 8192);            // prefetch W2b under G4h1
        #pragma unroll
        for (int ks = 0; ks < 4; ++ks) {
            const bf16x8 afr = *(const bf16x8*)&SCRw[c * 136 + ks*32 + g*8];
            #pragma unroll
            for (int nt = 0; nt < 4; ++nt) {
                const bf16x8 bfr = *(const bf16x8*)&L[BT + (16*nt + c)*136 + ks*32 + g*8];
                oacc[nt] = __builtin_amdgcn_mfma_f32_16x16x32_bf16(afr, bfr, oacc[nt], 0, 0, 0);
            }
        }
        #pragma unroll
        for (int nt = 0; nt < 4; ++nt) {
            const int d = 16*nt + c;
            const float bb = b2[d];
            #pragma unroll
            for (int r = 0; r < 4; ++r) {
                const float ov = oacc[nt][r] + bb;
                const float rv = bf2f(RELw[(4*g + r) * 136 + d]);
                sacc[r] = fmaf(ov, rv, sacc[r]);
            }
        }
    }
    __syncthreads();                                            // bar 10
    ST_WRITE136();                         // W2b -> BT
    __syncthreads();                                            // bar 11
    {
        f32x4 oacc[4] = {};
        #pragma unroll
        for (int ks = 0; ks < 4; ++ks) {
            const bf16x8 afr = *(const bf16x8*)&SCRw[c * 136 + ks*32 + g*8];
            #pragma unroll
            for (int nt = 0; nt < 4; ++nt) {
                const bf16x8 bfr = *(const bf16x8*)&L[BT + (16*nt + c)*136 + ks*32 + g*8];
                oacc[nt] = __builtin_amdgcn_mfma_f32_16x16x32_bf16(afr, bfr, oacc[nt], 0, 0, 0);
            }
        }
        #pragma unroll
        for (int nt = 0; nt < 4; ++nt) {
            const int d = 64 + 16*nt + c;
            const float bb = b2[d];
            #pragma unroll
            for (int r = 0; r < 4; ++r) {
                const float ov = oacc[nt][r] + bb;
                const float rv = bf2f(RELw[(4*g + r) * 136 + d]);
                sacc[r] = fmaf(ov, rv, sacc[r]);
            }
        }
    }
    #pragma unroll
    for (int r = 0; r < 4; ++r) {        // reduce over d (c-lanes)
        sacc[r] += __shfl_xor(sacc[r], 1);
        sacc[r] += __shfl_xor(sacc[r], 2);
        sacc[r] += __shfl_xor(sacc[r], 4);
        sacc[r] += __shfl_xor(sacc[r], 8);
    }
    if (c == 0) {
        #pragma unroll
        for (int r = 0; r < 4; ++r) {
            const int ga = a0 + 4*g + r;
            if (ga < A) scores[ga] = sacc[r];
        }
    }

    // ---- per-wave softmax partials over this wave's 16 actions ----
    {
        float m = -INFINITY;
        #pragma unroll
        for (int r = 0; r < 4; ++r)
            if (a0 + 4*g + r < A) m = fmaxf(m, sacc[r]);
        m = fmaxf(m, __shfl_xor(m, 16));
        m = fmaxf(m, __shfl_xor(m, 32));
        float es = 0.f;
        #pragma unroll
        for (int r = 0; r < 4; ++r)
            if (a0 + 4*g + r < A) es += __expf(sacc[r] - m);
        es += __shfl_xor(es, 16);
        es += __shfl_xor(es, 32);
        if (lane == 0) {
            const int idx = blockIdx.x * 4 + w;
            mb[idx] = m;
            sb[idx] = es;
        }
    }
}

// Combine per-wave (m, s) partials into global M and 1/S.
__global__ void k_combine(const float* __restrict__ mb, const float* __restrict__ sb,
                          int n, float* __restrict__ MS)
{
    __shared__ float red[256];
    const int tid = threadIdx.x;
    float m = -INFINITY;
    for (int i = tid; i < n; i += 256) m = fmaxf(m, mb[i]);
    red[tid] = m; __syncthreads();
    for (int s = 128; s > 0; s >>= 1) {
        if (tid < s) red[tid] = fmaxf(red[tid], red[tid + s]);
        __syncthreads();
    }
    const float M = red[0];
    __syncthreads();
    float sum = 0.f;
    for (int i = tid; i < n; i += 256) sum += sb[i] * __expf(mb[i] - M);
    red[tid] = sum; __syncthreads();
    for (int s = 128; s > 0; s >>= 1) {
        if (tid < s) red[tid] += red[tid + s];
        __syncthreads();
    }
    if (tid == 0) { MS[0] = M; MS[1] = 1.f / red[0]; }
}

// In-place: d_out holds raw scores; replace with softmax.
__global__ void k_norm(const float* __restrict__ scores, const float* __restrict__ MS,
                       float* __restrict__ out, int A)
{
    const int i = blockIdx.x * blockDim.x + threadIdx.x;
    if (i < A) out[i] = __expf(scores[i] - MS[0]) * MS[1];
}

extern "C" void kernel_launch(void* const* d_in, const int* in_sizes, int n_in,
                              void* d_out, int out_size, void* d_ws, size_t ws_size,
                              hipStream_t stream)
{
    const int*   action_ids = (const int*)  d_in[0];
    const float* emb        = (const float*)d_in[1];
    const float* Qg         = (const float*)d_in[2];
    const float* hist       = (const float*)d_in[3];
    const float* W1         = (const float*)d_in[4];
    const float* b1         = (const float*)d_in[5];
    const float* W2         = (const float*)d_in[6];
    const float* b2         = (const float*)d_in[7];
    float* out = (float*)d_out;
    const int A    = in_sizes[0];
    const int nblk = (A + BA - 1) / BA;
    const int npar = nblk * 4;                 // per-wave partials

    // Workspace (floats): h1[128] | MS[2] | pad | mb[npar] | sb[npar] | bf16 arena
    float* ws  = (float*)d_ws;
    float* h1  = ws;                           // 128
    float* MS  = ws + 128;                     // 2
    const int nal = (npar + 255) & ~255;       // 6400 for A=100000
    float* mbp = ws + 256;
    float* sbp = mbp + nal;
    ushort_t* u0   = (ushort_t*)(sbp + nal);   // 16B-aligned
    ushort_t* Qbf  = u0;                       // [64][128]  = 8192
    ushort_t* QTbf = u0 + 8192;                // [128][64]  = 8192
    ushort_t* W1bf = u0 + 16384;               // [128][128] = 16384
    ushort_t* W2bf = u0 + 32768;               // [128][128] = 16384
    (void)n_in; (void)out_size; (void)ws_size;

    k_cvt<<<193, 256, 0, stream>>>(Qg, W1, W2, hist, b1,
                                   Qbf, QTbf, W1bf, W2bf, h1);
    // raw scores land directly in d_out; normalized in-place afterwards
    k_main<<<nblk, NTHR, 0, stream>>>(action_ids, emb, b2, h1,
                                      Qbf, QTbf, W1bf, W2bf,
                                      out, mbp, sbp, A);
    k_combine<<<1, 256, 0, stream>>>(mbp, sbp, npar, MS);
    k_norm<<<(A + 255) / 256, 256, 0, stream>>>(out, MS, out, A);
}